// Round 10
// baseline (156.075 us; speedup 1.0000x reference)
//
#include <hip/hip_runtime.h>

// MaskTypeProbabilitiesLayer, R10: two-kernel split through workspace.
//   Kernel A: per-row read stream -> compact gt (8 MB) + first5/first6 (8 KB).
//   Kernel B: fill-style dense write stream of the 67 MB int32 0/1 mask.
// Rationale: R6-R9 monolithic kernel pinned at ~2 TB/s mixed; harness's own
// 352 MB poison fill sustains 6.8 TB/s on this machine with a pure
// grid-stride write stream -> emulate that regime per phase.
//
// Bit-packed masks: TYPE_TABLE[0]=0x02 [1]=0x06 [2]=0x10 [3]=0xF8 [7]=0x80;
//   NO_TIMESIGN=0x20 NO_TEMPO=0x40 FULL=0xF8.

#define SEQ_L 2048
#define NF 11

// ---------------- Kernel A: extract + reduce ----------------
// One block per row (1024 x 512). Row = 5632 int4; 11 per thread, all loads
// issued before consumption (R9's MLP fix; VGPR ~60 is the signature).
__global__ __launch_bounds__(512)
void mask_reduce_kernel(const int* __restrict__ in, int* __restrict__ gt_out,
                        unsigned* __restrict__ first5, unsigned* __restrict__ first6) {
    __shared__ unsigned s_f5, s_f6;
    const int b   = blockIdx.x;
    const int tid = threadIdx.x;
    if (tid == 0) { s_f5 = 0xFFFFFFFFu; s_f6 = 0xFFFFFFFFu; }
    __syncthreads();

    const int4* rowv = (const int4*)(in + (size_t)b * SEQ_L * NF);
    int4 v[11];
    #pragma unroll
    for (int p = 0; p < 11; ++p) v[p] = rowv[tid + p * 512];

    unsigned f5 = 0xFFFFFFFFu, f6 = 0xFFFFFFFFu;
    int* grow = gt_out + b * SEQ_L;
    #pragma unroll
    for (int p = 0; p < 11; ++p) {
        const int i4 = tid + p * 512;
        const int j  = i4 * 4;
        const int mi  = (j + 10) / 11;     // at most one multiple of 11 per 4-window
        const int pos = mi * 11 - j;       // 0..10
        if (pos < 4) {
            const int gv = (pos == 0) ? v[p].x : (pos == 1) ? v[p].y
                         : (pos == 2) ? v[p].z : v[p].w;
            grow[mi] = gv;                 // dense-ish 8 KB/row write
            if (gv == 5) f5 = min(f5, (unsigned)mi);
            if (gv == 6) f6 = min(f6, (unsigned)mi);
        }
    }
    #pragma unroll
    for (int off = 32; off >= 1; off >>= 1) {
        f5 = min(f5, (unsigned)__shfl_xor((int)f5, off, 64));
        f6 = min(f6, (unsigned)__shfl_xor((int)f6, off, 64));
    }
    if ((tid & 63) == 0) {
        if (f5 != 0xFFFFFFFFu) atomicMin(&s_f5, f5);
        if (f6 != 0xFFFFFFFFu) atomicMin(&s_f6, f6);
    }
    __syncthreads();
    if (tid == 0) { first5[b] = s_f5; first6[b] = s_f6; }   // absent => 0xFFFFFFFF (+inf)
}

// ---------------- Kernel B: dense emit ----------------
// 4096 blocks x 256 threads; block handles 1024 of its row's 4096 int4 chunks.
// Pure write stream: 66 MB int4 stores; reads 8 MB compact gt (LLC).
__global__ __launch_bounds__(256)
void mask_emit_kernel(const int* __restrict__ gt, const unsigned* __restrict__ first5,
                      const unsigned* __restrict__ first6, int* __restrict__ out) {
    const int bid = blockIdx.x;
    const int row = bid >> 2;            // 4 blocks per row
    const int tid = threadIdx.x;
    const unsigned f5 = first5[row];     // uniform -> scalar load
    const unsigned f6 = first6[row];
    const int* grow = gt + row * SEQ_L;
    int4* orow = (int4*)(out + (size_t)row * SEQ_L * 8);
    const int cbase = (bid & 3) * 1024;

    const unsigned long long pack = 0x80000000F8100602ULL;

    #pragma unroll
    for (int k = 0; k < 4; ++k) {
        const int cr   = cbase + k * 256 + tid;   // 0..4095, lane-dense
        const int t    = cr >> 1;
        const int half = cr & 1;
        const int gv   = grow[t];                 // lane pairs share (broadcast)
        unsigned m;
        if (gv >= 4 && gv <= 6) {
            const unsigned idx = (unsigned)((t + 1 < SEQ_L - 1) ? (t + 1) : (SEQ_L - 1));
            m = (f5 > idx) ? 0x20u : ((f6 > idx) ? 0x40u : 0xF8u);
        } else {
            const int gc = gv < 0 ? 0 : (gv > 8 ? 8 : gv);
            m = (gc >= 8) ? 0u : (unsigned)((pack >> (gc * 8)) & 0xFFu);
        }
        const unsigned nib = half ? (m >> 4) : m;
        int4 w;
        w.x = (int)((nib >> 0) & 1u);
        w.y = (int)((nib >> 1) & 1u);
        w.z = (int)((nib >> 2) & 1u);
        w.w = (int)((nib >> 3) & 1u);
        orow[cr] = w;
    }
}

extern "C" void kernel_launch(void* const* d_in, const int* in_sizes, int n_in,
                              void* d_out, int out_size, void* d_ws, size_t ws_size,
                              hipStream_t stream) {
    const int* in = (const int*)d_in[0];
    int* out = (int*)d_out;
    const int batch = in_sizes[0] / (SEQ_L * NF);   // 1024

    // Workspace layout: [first5: batch u32][first6: batch u32][gt: batch*SEQ_L i32]
    unsigned* first5 = (unsigned*)d_ws;
    unsigned* first6 = first5 + batch;
    int* gt = (int*)(first6 + batch);

    mask_reduce_kernel<<<batch, 512, 0, stream>>>(in, gt, first5, first6);
    mask_emit_kernel<<<batch * 4, 256, 0, stream>>>(gt, first5, first6, out);
}

// Round 11
// 152.981 us; speedup vs baseline: 1.0202x; 1.0202x over previous
//
#include <hip/hip_runtime.h>

// MaskTypeProbabilitiesLayer: per (b,t) produce 8-wide 0/1 mask (int32 out).
//   gt = in[b,t,0]; base = TYPE_TABLE[gt]; gt in {4,5,6} -> dynamic mask from
//   first-occurrence index of 5 / 6 vs idx = min(t+1, L-1).
// Bit-packed: TYPE_TABLE[0]=0x02 [1]=0x06 [2]=0x10 [3]=0xF8 [7]=0x80;
//   NO_TIMESIGN=0x20 NO_TEMPO=0x40 FULL=0xF8.
//
// History: R6-R8 ~2 TB/s regardless of occupancy/pattern; R8 counter showed
// VGPR_Count=12 DESPITE v[11] array => compiler re-fused load+consume loops,
// per-thread read MLP ~1 the whole time. R9 dense stores: 55->50 us. R10
// two-kernel split: neutral (read kernel ~2.4 TB/s is the pinned resource).
// R11: sched_barrier(0) between load issuance and consumption — scheduler
// cannot sink loads across it, forcing all 11 int4 (44 VGPR) in flight.
// Signature: VGPR_Count >= 56.

#define SEQ_L 2048
#define NF 11
#define BLOCK 512
#define PASSES 11                    // 5632 int4 per row / 512 threads
#define OPASS 8                      // 4096 out-int4 per row / 512 threads

__global__ __launch_bounds__(BLOCK)
void mask_type_prob_kernel(const int* __restrict__ in, int* __restrict__ out) {
    __shared__ int s_gt[SEQ_L];
    __shared__ unsigned s_f5, s_f6;

    const int b   = blockIdx.x;
    const int tid = threadIdx.x;

    if (tid == 0) { s_f5 = 0xFFFFFFFFu; s_f6 = 0xFFFFFFFFu; }
    __syncthreads();

    const int4* rowv = (const int4*)(in + (size_t)b * SEQ_L * NF);

    // ---- Phase 1a: issue ALL 11 loads; barrier pins them before any use ----
    int4 v[PASSES];
    #pragma unroll
    for (int p = 0; p < PASSES; ++p) {
        v[p] = rowv[tid + p * BLOCK];
    }
    __builtin_amdgcn_sched_barrier(0);   // do NOT let the scheduler re-fuse

    // ---- Phase 1b: extract feature-0, stage to LDS, track first 5/6 ----
    unsigned f5 = 0xFFFFFFFFu, f6 = 0xFFFFFFFFu;
    #pragma unroll
    for (int p = 0; p < PASSES; ++p) {
        const int i4 = tid + p * BLOCK;   // 0..5631
        const int j  = i4 * 4;            // int index of v[p].x
        const int mi  = (j + 10) / 11;    // at most one multiple of 11 in [j,j+4)
        const int pos = mi * 11 - j;      // 0..10
        if (pos < 4) {
            const int gv = (pos == 0) ? v[p].x : (pos == 1) ? v[p].y
                         : (pos == 2) ? v[p].z : v[p].w;
            s_gt[mi] = gv;
            if (gv == 5) f5 = min(f5, (unsigned)mi);
            if (gv == 6) f6 = min(f6, (unsigned)mi);
        }
    }

    // Wave min-reduce, one LDS atomic per wave.
    #pragma unroll
    for (int off = 32; off >= 1; off >>= 1) {
        f5 = min(f5, (unsigned)__shfl_xor((int)f5, off, 64));
        f6 = min(f6, (unsigned)__shfl_xor((int)f6, off, 64));
    }
    if ((tid & 63) == 0) {
        if (f5 != 0xFFFFFFFFu) atomicMin(&s_f5, f5);
        if (f6 != 0xFFFFFFFFu) atomicMin(&s_f6, f6);
    }
    __syncthreads();

    const unsigned first5 = s_f5;
    const unsigned first6 = s_f6;

    const unsigned long long pack = 0x80000000F8100602ULL;

    // ---- Phase 2: lane-dense int4 stores (chunk c = 16B half of pos c>>1) ----
    int4* orowv = (int4*)(out + (size_t)b * SEQ_L * 8);

    #pragma unroll
    for (int k = 0; k < OPASS; ++k) {
        const int c    = tid + k * BLOCK;  // 0..4095, lanes contiguous
        const int t    = c >> 1;
        const int half = c & 1;
        const int gv   = s_gt[t];          // 2-way LDS aliasing: free
        unsigned m;
        if (gv >= 4 && gv <= 6) {
            const unsigned idx = (unsigned)((t + 1 < SEQ_L - 1) ? (t + 1) : (SEQ_L - 1));
            m = (first5 > idx) ? 0x20u : ((first6 > idx) ? 0x40u : 0xF8u);
        } else {
            const int gc = gv < 0 ? 0 : (gv > 8 ? 8 : gv);
            m = (gc >= 8) ? 0u : (unsigned)((pack >> (gc * 8)) & 0xFFu);
        }
        const unsigned nib = half ? (m >> 4) : m;
        int4 w;
        w.x = (int)((nib >> 0) & 1u);
        w.y = (int)((nib >> 1) & 1u);
        w.z = (int)((nib >> 2) & 1u);
        w.w = (int)((nib >> 3) & 1u);
        orowv[c] = w;
    }
}

extern "C" void kernel_launch(void* const* d_in, const int* in_sizes, int n_in,
                              void* d_out, int out_size, void* d_ws, size_t ws_size,
                              hipStream_t stream) {
    const int* in = (const int*)d_in[0];
    int* out = (int*)d_out;
    const int batch = in_sizes[0] / (SEQ_L * NF);   // 1024
    mask_type_prob_kernel<<<batch, BLOCK, 0, stream>>>(in, out);
}